// Round 9
// baseline (363.846 us; speedup 1.0000x reference)
//
#include <hip/hip_runtime.h>
#include <hip/hip_bf16.h>

typedef unsigned short u16;
typedef unsigned int u32;
typedef __attribute__((ext_vector_type(8))) short bf16x8;   // 8 bf16 (4 VGPRs)
typedef __attribute__((ext_vector_type(4))) short s16x4;
typedef __attribute__((ext_vector_type(4))) float f32x4;

#define NN 4096

__device__ __forceinline__ u16 f2bf(float f) {
    union { float f; u32 u; } v; v.f = f;
    u32 r = v.u + 0x7fffu + ((v.u >> 16) & 1u);   // RNE (inputs finite)
    return (u16)(r >> 16);
}

// ---------------- K1: deg = rowsum(A); inv_d = 1/(deg+1) ----------------
__global__ void rowsum_kernel(const float* __restrict__ A, float* __restrict__ invd) {
    const int row = blockIdx.x;
    const float4* a4 = reinterpret_cast<const float4*>(A + (size_t)row * NN);
    float s = 0.f;
    #pragma unroll
    for (int i = 0; i < 4; ++i) {
        float4 v = a4[threadIdx.x + i * 256];
        s += v.x + v.y + v.z + v.w;
    }
    #pragma unroll
    for (int off = 32; off > 0; off >>= 1) s += __shfl_down(s, off, 64);
    __shared__ float ws[4];
    if ((threadIdx.x & 63) == 0) ws[threadIdx.x >> 6] = s;
    __syncthreads();
    if (threadIdx.x == 0) {
        float t = ws[0] + ws[1] + ws[2] + ws[3];
        invd[row] = 1.0f / (t + 1.0f);
    }
}

// ------- K2: temp = 0.5*h + 0.5*(A + I)*inv_d[col]  -> bf16 [M][K] -------
__global__ void make_temp_kernel(const float* __restrict__ A, const float* __restrict__ h,
                                 const float* __restrict__ invd, u16* __restrict__ T) {
    const size_t g = ((size_t)blockIdx.x * 256 + threadIdx.x) * 8;
    const int row = (int)(g >> 12);
    const int col = (int)(g & 4095);
    const float4* a4 = reinterpret_cast<const float4*>(A + g);
    const float4* h4 = reinterpret_cast<const float4*>(h + g);
    const float4* d4 = reinterpret_cast<const float4*>(invd + col);
    float4 a0 = a4[0], a1 = a4[1];
    float4 h0 = h4[0], h1 = h4[1];
    float4 dd0 = d4[0], dd1 = d4[1];
    float av[8] = {a0.x,a0.y,a0.z,a0.w,a1.x,a1.y,a1.z,a1.w};
    float hv[8] = {h0.x,h0.y,h0.z,h0.w,h1.x,h1.y,h1.z,h1.w};
    float dv[8] = {dd0.x,dd0.y,dd0.z,dd0.w,dd1.x,dd1.y,dd1.z,dd1.w};
    bf16x8 o;
    #pragma unroll
    for (int j = 0; j < 8; ++j) {
        float aa = av[j] + ((col + j == row) ? 1.0f : 0.0f);
        float t = 0.5f * hv[j] + 0.5f * aa * dv[j];
        o[j] = (short)f2bf(t);
    }
    *reinterpret_cast<bf16x8*>(T + g) = o;
}

// --------- K3: Wt[n][k] = bf16(W[k][n])  (LDS 64x64 tile transpose) ---------
__global__ void transposeW_kernel(const float* __restrict__ W, u16* __restrict__ Wt) {
    __shared__ float tile[64][65];
    const int nt = blockIdx.x & 63;
    const int kt = blockIdx.x >> 6;
    const int k0 = kt * 64, n0 = nt * 64;
    const int tr = threadIdx.x >> 4;          // 0..15
    const int tc = (threadIdx.x & 15) * 4;    // 0..60
    #pragma unroll
    for (int rr = 0; rr < 64; rr += 16) {
        float4 v = *reinterpret_cast<const float4*>(&W[(size_t)(k0 + tr + rr) * NN + n0 + tc]);
        tile[tr + rr][tc + 0] = v.x;
        tile[tr + rr][tc + 1] = v.y;
        tile[tr + rr][tc + 2] = v.z;
        tile[tr + rr][tc + 3] = v.w;
    }
    __syncthreads();
    #pragma unroll
    for (int rr = 0; rr < 64; rr += 16) {
        const int n = tr + rr;
        s16x4 o;
        #pragma unroll
        for (int j = 0; j < 4; ++j) o[j] = (short)f2bf(tile[tc + j][n]);
        *reinterpret_cast<s16x4*>(&Wt[(size_t)(n0 + n) * NN + k0 + tc]) = o;
    }
}

// ============ K4: C[M][N] = temp[M][K] @ Wt[N][K]^T (bf16 MFMA) ============
// R9 = R5 structure (BK=64, 2 LDS bufs, vmcnt(0) at full-step distance)
// with B READ DIRECTLY FROM GLOBAL into registers (L2-served, ping-pong
// prefetch one K-tile ahead). Halves DS-pipe reads (192->96 b128/tile) and
// staging writes; DS total ~1920 cy < MFMA wall 2483 cy. LDS = 64 KB.

#define GLD16(g, l) __builtin_amdgcn_global_load_lds( \
    (const __attribute__((address_space(1))) void*)(g), \
    (__attribute__((address_space(3))) void*)(l), 16, 0, 0)

__global__ __launch_bounds__(512) void gemm_kernel(
    const u16* __restrict__ Atl,   // [M][K] bf16 (temp)
    const u16* __restrict__ Btl,   // [N][K] bf16 (Wt)
    float* __restrict__ C)         // [M][N] f32
{
    __shared__ u16 SA[2][16384];   // [buf][256 rows x 64 k] = 64 KiB

    const int tid  = threadIdx.x;
    const int wid  = tid >> 6;     // 0..7
    const int lane = tid & 63;
    const int llo  = lane & 15;
    const int lhi  = lane >> 4;    // 0..3
    const int wr   = wid >> 2;     // 0..1  (M half: 128 rows)
    const int wc   = wid & 3;      // 0..3  (N quarter: 64 cols)

    // XCD swizzle (grid=256, 256%8==0 -> bijective); 16 consecutive swz
    // blocks share bn -> B panel (2MB) stays hot in the XCD's L2.
    const int swz = ((int)blockIdx.x & 7) * 32 + ((int)blockIdx.x >> 3);
    const int bm = swz >> 4, bn = swz & 15;
    const int tileRow = bm * 256, tileCol = bn * 256;

    // ---- A staging (R5-proven): linear LDS dest, inverse-swizzled source ----
    const int r0 = tid >> 3;                                // 0..63
    const int kc = (((tid & 7) ^ (r0 & 7)) << 3);
    const u16* gA = Atl + (size_t)(tileRow + r0) * NN + kc;

    #define STAGE_A(BUF, KOFF) do { \
        _Pragma("unroll") \
        for (int i = 0; i < 4; ++i) \
            GLD16(gA + (size_t)(i * 64) * NN + (KOFF), &SA[BUF][i * 4096 + tid * 8]); \
    } while (0)

    // ---- A read offsets (swizzled, R5-proven 0 conflicts; ks1 = off^32) ----
    int offA[8];
    #pragma unroll
    for (int m = 0; m < 8; ++m) {
        const int row = wr * 128 + m * 16 + llo;
        offA[m] = row * 64 + ((lhi ^ (row & 7)) << 3);
    }

    // ---- B direct-from-global per-lane row pointers ----
    const u16* gBr[4];
    #pragma unroll
    for (int n = 0; n < 4; ++n)
        gBr[n] = Btl + (size_t)(tileCol + wc * 64 + n * 16 + llo) * NN + lhi * 8;

    #define BLOAD(SET, KB) do { \
        _Pragma("unroll") \
        for (int n = 0; n < 4; ++n) { \
            SET[n][0] = *reinterpret_cast<const bf16x8*>(gBr[n] + (KB)); \
            SET[n][1] = *reinterpret_cast<const bf16x8*>(gBr[n] + (KB) + 32); \
        } } while (0)

    f32x4 acc[8][4];
    #pragma unroll
    for (int m = 0; m < 8; ++m)
        #pragma unroll
        for (int n = 0; n < 4; ++n)
            acc[m][n] = (f32x4){0.f, 0.f, 0.f, 0.f};

    bf16x8 bE[4][2], bO[4][2];   // ping-pong B sets (static indexing only)

    // ---- prologue: stage A(0) -> buf0, load B(0) -> bE ----
    STAGE_A(0, 0);
    BLOAD(bE, 0);
    asm volatile("s_waitcnt vmcnt(0)" ::: "memory");
    __builtin_amdgcn_s_barrier();
    asm volatile("" ::: "memory");

    // STEP(T): stage A(T+1), MFMA ks0 (B cur), load B(T+1) mid-step,
    //          read A ks1, MFMA ks1, vmcnt(0)+barrier (full-step distance).
    #define STEP(T, BC, BNX) do { \
        const int t_ = (T); \
        const bool nlast_ = t_ < 63; \
        if (nlast_) STAGE_A((t_ + 1) & 1, (t_ + 1) * 64); \
        __builtin_amdgcn_sched_barrier(0); \
        const u16* sA = &SA[t_ & 1][0]; \
        bf16x8 af[8]; \
        _Pragma("unroll") \
        for (int m = 0; m < 8; ++m) af[m] = *reinterpret_cast<const bf16x8*>(sA + offA[m]); \
        __builtin_amdgcn_s_setprio(1); \
        _Pragma("unroll") \
        for (int m = 0; m < 8; ++m) \
            _Pragma("unroll") \
            for (int n = 0; n < 4; ++n) \
                acc[m][n] = __builtin_amdgcn_mfma_f32_16x16x32_bf16(af[m], BC[n][0], acc[m][n], 0, 0, 0); \
        __builtin_amdgcn_s_setprio(0); \
        if (nlast_) BLOAD(BNX, (t_ + 1) * 64); \
        _Pragma("unroll") \
        for (int m = 0; m < 8; ++m) af[m] = *reinterpret_cast<const bf16x8*>(sA + (offA[m] ^ 32)); \
        __builtin_amdgcn_s_setprio(1); \
        _Pragma("unroll") \
        for (int m = 0; m < 8; ++m) \
            _Pragma("unroll") \
            for (int n = 0; n < 4; ++n) \
                acc[m][n] = __builtin_amdgcn_mfma_f32_16x16x32_bf16(af[m], BC[n][1], acc[m][n], 0, 0, 0); \
        __builtin_amdgcn_s_setprio(0); \
        if (nlast_) { \
            asm volatile("s_waitcnt vmcnt(0)" ::: "memory"); \
            __builtin_amdgcn_s_barrier(); \
            asm volatile("" ::: "memory"); \
        } \
    } while (0)

    #pragma unroll 1
    for (int tt = 0; tt < 32; ++tt) {
        STEP(2 * tt,     bE, bO);   // even: consume E, fill O
        STEP(2 * tt + 1, bO, bE);   // odd : consume O, fill E
    }
    #undef STEP
    #undef BLOAD
    #undef STAGE_A

    // ---- epilogue: C/D layout col=lane&15, row=(lane>>4)*4+reg ----
    #pragma unroll
    for (int m = 0; m < 8; ++m) {
        #pragma unroll
        for (int n = 0; n < 4; ++n) {
            const size_t rbase = (size_t)(tileRow + wr * 128 + m * 16 + lhi * 4) * NN
                               + tileCol + wc * 64 + n * 16 + llo;
            #pragma unroll
            for (int j = 0; j < 4; ++j)
                C[rbase + (size_t)j * NN] = acc[m][n][j];
        }
    }
}

// ---------------------------------------------------------------------------
extern "C" void kernel_launch(void* const* d_in, const int* in_sizes, int n_in,
                              void* d_out, int out_size, void* d_ws, size_t ws_size,
                              hipStream_t stream) {
    const float* A = (const float*)d_in[0];
    const float* h = (const float*)d_in[1];
    const float* W = (const float*)d_in[2];
    float* out = (float*)d_out;

    // workspace layout: inv_d (16KB) | temp bf16 (32MB) | Wt bf16 (32MB)
    float* invd = (float*)d_ws;
    u16* temp = (u16*)((char*)d_ws + 16384);
    u16* wt   = temp + (size_t)NN * NN;

    rowsum_kernel<<<NN, 256, 0, stream>>>(A, invd);
    make_temp_kernel<<<(NN * (size_t)NN) / (256 * 8), 256, 0, stream>>>(A, h, invd, temp);
    transposeW_kernel<<<(NN / 64) * (NN / 64), 256, 0, stream>>>(W, wt);
    gemm_kernel<<<256, 512, 0, stream>>>(temp, wt, out);
}

// Round 10
// 184.198 us; speedup vs baseline: 1.9753x; 1.9753x over previous
//
#include <hip/hip_runtime.h>
#include <hip/hip_bf16.h>

typedef unsigned short u16;
typedef unsigned int u32;
typedef __attribute__((ext_vector_type(8))) short bf16x8;   // 8 bf16 (4 VGPRs)
typedef __attribute__((ext_vector_type(4))) short s16x4;
typedef __attribute__((ext_vector_type(4))) float f32x4;

#define NN 4096

__device__ __forceinline__ u16 f2bf(float f) {
    union { float f; u32 u; } v; v.f = f;
    u32 r = v.u + 0x7fffu + ((v.u >> 16) & 1u);   // RNE (inputs finite)
    return (u16)(r >> 16);
}

// ---------------- K1: deg = rowsum(A); inv_d = 1/(deg+1) ----------------
__global__ void rowsum_kernel(const float* __restrict__ A, float* __restrict__ invd) {
    const int row = blockIdx.x;
    const float4* a4 = reinterpret_cast<const float4*>(A + (size_t)row * NN);
    float s = 0.f;
    #pragma unroll
    for (int i = 0; i < 4; ++i) {
        float4 v = a4[threadIdx.x + i * 256];
        s += v.x + v.y + v.z + v.w;
    }
    #pragma unroll
    for (int off = 32; off > 0; off >>= 1) s += __shfl_down(s, off, 64);
    __shared__ float ws[4];
    if ((threadIdx.x & 63) == 0) ws[threadIdx.x >> 6] = s;
    __syncthreads();
    if (threadIdx.x == 0) {
        float t = ws[0] + ws[1] + ws[2] + ws[3];
        invd[row] = 1.0f / (t + 1.0f);
    }
}

// ------- K2: temp = 0.5*h + 0.5*(A + I)*inv_d[col]  -> bf16 [M][K] -------
__global__ void make_temp_kernel(const float* __restrict__ A, const float* __restrict__ h,
                                 const float* __restrict__ invd, u16* __restrict__ T) {
    const size_t g = ((size_t)blockIdx.x * 256 + threadIdx.x) * 8;
    const int row = (int)(g >> 12);
    const int col = (int)(g & 4095);
    const float4* a4 = reinterpret_cast<const float4*>(A + g);
    const float4* h4 = reinterpret_cast<const float4*>(h + g);
    const float4* d4 = reinterpret_cast<const float4*>(invd + col);
    float4 a0 = a4[0], a1 = a4[1];
    float4 h0 = h4[0], h1 = h4[1];
    float4 dd0 = d4[0], dd1 = d4[1];
    float av[8] = {a0.x,a0.y,a0.z,a0.w,a1.x,a1.y,a1.z,a1.w};
    float hv[8] = {h0.x,h0.y,h0.z,h0.w,h1.x,h1.y,h1.z,h1.w};
    float dv[8] = {dd0.x,dd0.y,dd0.z,dd0.w,dd1.x,dd1.y,dd1.z,dd1.w};
    bf16x8 o;
    #pragma unroll
    for (int j = 0; j < 8; ++j) {
        float aa = av[j] + ((col + j == row) ? 1.0f : 0.0f);
        float t = 0.5f * hv[j] + 0.5f * aa * dv[j];
        o[j] = (short)f2bf(t);
    }
    *reinterpret_cast<bf16x8*>(T + g) = o;
}

// --------- K3: Wt[n][k] = bf16(W[k][n])  (LDS 64x64 tile transpose) ---------
__global__ void transposeW_kernel(const float* __restrict__ W, u16* __restrict__ Wt) {
    __shared__ float tile[64][65];
    const int nt = blockIdx.x & 63;
    const int kt = blockIdx.x >> 6;
    const int k0 = kt * 64, n0 = nt * 64;
    const int tr = threadIdx.x >> 4;          // 0..15
    const int tc = (threadIdx.x & 15) * 4;    // 0..60
    #pragma unroll
    for (int rr = 0; rr < 64; rr += 16) {
        float4 v = *reinterpret_cast<const float4*>(&W[(size_t)(k0 + tr + rr) * NN + n0 + tc]);
        tile[tr + rr][tc + 0] = v.x;
        tile[tr + rr][tc + 1] = v.y;
        tile[tr + rr][tc + 2] = v.z;
        tile[tr + rr][tc + 3] = v.w;
    }
    __syncthreads();
    #pragma unroll
    for (int rr = 0; rr < 64; rr += 16) {
        const int n = tr + rr;
        s16x4 o;
        #pragma unroll
        for (int j = 0; j < 4; ++j) o[j] = (short)f2bf(tile[tc + j][n]);
        *reinterpret_cast<s16x4*>(&Wt[(size_t)(n0 + n) * NN + k0 + tc]) = o;
    }
}

// ============ K4: C[M][N] = temp[M][K] @ Wt[N][K]^T (bf16 MFMA) ============
// R10: 128x128 tile, 4 waves (2x2), BK=64, double-buffer 64KB LDS ->
// 2 blocks/CU resident. Cross-block DS/MFMA pipe overlap (m114/m97 mechanism)
// replaces all the failed intra-block phase schedules. Internals from R5:
// XOR-8 swizzle (0 conflicts), linear-dest gload_lds staging, one
// vmcnt(0)+barrier per K64 step (full-step issue-to-wait distance), setprio.

#define GLD16(g, l) __builtin_amdgcn_global_load_lds( \
    (const __attribute__((address_space(1))) void*)(g), \
    (__attribute__((address_space(3))) void*)(l), 16, 0, 0)

__global__ __launch_bounds__(256) void gemm_kernel(
    const u16* __restrict__ Atl,   // [M][K] bf16 (temp)
    const u16* __restrict__ Btl,   // [N][K] bf16 (Wt)
    float* __restrict__ C)         // [M][N] f32
{
    __shared__ u16 S[2][2][8192];  // [buf][A=0/B=1][128 rows x 64 k] = 64 KiB

    const int tid  = threadIdx.x;
    const int wid  = tid >> 6;     // 0..3
    const int lane = tid & 63;
    const int llo  = lane & 15;
    const int lhi  = lane >> 4;    // 0..3
    const int wr   = wid >> 1;     // 0..1  (M half: 64 rows)
    const int wc   = wid & 1;      // 0..1  (N half: 64 cols)

    // XCD swizzle (grid=1024, 1024%8==0 -> bijective)
    const int swz = ((int)blockIdx.x & 7) * 128 + ((int)blockIdx.x >> 3);
    const int bm = swz >> 5, bn = swz & 31;
    const int tileRow = bm * 128, tileCol = bn * 128;

    // ---- staging: linear LDS dest, inverse-swizzled global source ----
    // per instr: 256 thr x 16B = 4KB = 32 rows x 64 elems.
    // row = i*32 + (tid>>3); (i*32)&7==0 -> row&7 = (tid>>3)&7.
    const int r0 = tid >> 3;                                // 0..31
    const int kc = (((tid & 7) ^ (r0 & 7)) << 3);
    const u16* gA = Atl + (size_t)(tileRow + r0) * NN + kc;
    const u16* gB = Btl + (size_t)(tileCol + r0) * NN + kc;

    #define STAGE(BUF, KOFF) do { \
        _Pragma("unroll") \
        for (int i = 0; i < 4; ++i) { \
            GLD16(gA + (size_t)(i * 32) * NN + (KOFF), &S[BUF][0][i * 2048 + tid * 8]); \
            GLD16(gB + (size_t)(i * 32) * NN + (KOFF), &S[BUF][1][i * 2048 + tid * 8]); \
        } } while (0)

    // ---- swizzled read offsets (elements; ks1 = off ^ 32) ----
    int offA[4], offB[4];
    #pragma unroll
    for (int m = 0; m < 4; ++m) {
        const int row = wr * 64 + m * 16 + llo;
        offA[m] = row * 64 + ((lhi ^ (row & 7)) << 3);
    }
    #pragma unroll
    for (int n = 0; n < 4; ++n) {
        const int row = wc * 64 + n * 16 + llo;
        offB[n] = row * 64 + ((lhi ^ (row & 7)) << 3);
    }

    f32x4 acc[4][4];
    #pragma unroll
    for (int m = 0; m < 4; ++m)
        #pragma unroll
        for (int n = 0; n < 4; ++n)
            acc[m][n] = (f32x4){0.f, 0.f, 0.f, 0.f};

    // ---- prologue: stage tile 0 into buf 0 ----
    STAGE(0, 0);
    asm volatile("s_waitcnt vmcnt(0)" ::: "memory");
    __builtin_amdgcn_s_barrier();
    asm volatile("" ::: "memory");

    // ---- main loop: 64 K-steps of 64 ----
    #pragma unroll 1
    for (int t = 0; t < 64; ++t) {
        if (t < 63) STAGE((t + 1) & 1, (t + 1) * 64);
        __builtin_amdgcn_sched_barrier(0);   // pin stage-issue before compute

        const u16* sA = &S[t & 1][0][0];
        const u16* sB = &S[t & 1][1][0];

        bf16x8 bv[4][2], af[4];
        #pragma unroll
        for (int n = 0; n < 4; ++n) {
            bv[n][0] = *reinterpret_cast<const bf16x8*>(sB + offB[n]);
            bv[n][1] = *reinterpret_cast<const bf16x8*>(sB + (offB[n] ^ 32));
        }
        #pragma unroll
        for (int m = 0; m < 4; ++m)
            af[m] = *reinterpret_cast<const bf16x8*>(sA + offA[m]);

        __builtin_amdgcn_s_setprio(1);
        #pragma unroll
        for (int m = 0; m < 4; ++m)
            #pragma unroll
            for (int n = 0; n < 4; ++n)
                acc[m][n] = __builtin_amdgcn_mfma_f32_16x16x32_bf16(
                    af[m], bv[n][0], acc[m][n], 0, 0, 0);
        __builtin_amdgcn_s_setprio(0);

        #pragma unroll
        for (int m = 0; m < 4; ++m)
            af[m] = *reinterpret_cast<const bf16x8*>(sA + (offA[m] ^ 32));

        __builtin_amdgcn_s_setprio(1);
        #pragma unroll
        for (int m = 0; m < 4; ++m)
            #pragma unroll
            for (int n = 0; n < 4; ++n)
                acc[m][n] = __builtin_amdgcn_mfma_f32_16x16x32_bf16(
                    af[m], bv[n][1], acc[m][n], 0, 0, 0);
        __builtin_amdgcn_s_setprio(0);

        // loads for tile t+1 were issued a full step ago; with 2 blocks/CU
        // the residual drain hides under the other block's compute.
        if (t < 63) {
            asm volatile("s_waitcnt vmcnt(0)" ::: "memory");
            __builtin_amdgcn_s_barrier();
            asm volatile("" ::: "memory");
        }
    }
    #undef STAGE

    // ---- epilogue: C/D layout col=lane&15, row=(lane>>4)*4+reg ----
    #pragma unroll
    for (int m = 0; m < 4; ++m) {
        #pragma unroll
        for (int n = 0; n < 4; ++n) {
            const size_t rbase = (size_t)(tileRow + wr * 64 + m * 16 + lhi * 4) * NN
                               + tileCol + wc * 64 + n * 16 + llo;
            #pragma unroll
            for (int j = 0; j < 4; ++j)
                C[rbase + (size_t)j * NN] = acc[m][n][j];
        }
    }
}

// ---------------------------------------------------------------------------
extern "C" void kernel_launch(void* const* d_in, const int* in_sizes, int n_in,
                              void* d_out, int out_size, void* d_ws, size_t ws_size,
                              hipStream_t stream) {
    const float* A = (const float*)d_in[0];
    const float* h = (const float*)d_in[1];
    const float* W = (const float*)d_in[2];
    float* out = (float*)d_out;

    // workspace layout: inv_d (16KB) | temp bf16 (32MB) | Wt bf16 (32MB)
    float* invd = (float*)d_ws;
    u16* temp = (u16*)((char*)d_ws + 16384);
    u16* wt   = temp + (size_t)NN * NN;

    rowsum_kernel<<<NN, 256, 0, stream>>>(A, invd);
    make_temp_kernel<<<(NN * (size_t)NN) / (256 * 8), 256, 0, stream>>>(A, h, invd, temp);
    transposeW_kernel<<<(NN / 64) * (NN / 64), 256, 0, stream>>>(W, wt);
    gemm_kernel<<<1024, 256, 0, stream>>>(temp, wt, out);
}